// Round 3
// baseline (841.320 us; speedup 1.0000x reference)
//
#include <hip/hip_runtime.h>

constexpr float kAlpha = 0.1f;
constexpr float kBeta  = 1.1f;
constexpr int   kC     = 16;
constexpr int   kD     = 512;
constexpr float kEps   = 1e-8f;

// ws layout (float offsets)
constexpr int SUMS_OFF = 0;       // kC*kD = 8192
constexpr int CNT_OFF  = 8192;    // 16
constexpr int TOT_OFF  = 8208;    // 1
constexpr int CTR1_OFF = 8209;    // int: k1 completion counter
constexpr int CTR2_OFF = 8210;    // int: k3 completion counter
constexpr int PDM_OFF  = 8960;    // 256 floats scratch (pair distances)
constexpr int CN_OFF   = 9216;    // 8192 (16B aligned)
constexpr int MSK_OFF  = 17408;   // 16 unsigned
constexpr int SCL_OFF  = 17424;   // [0]=denom, [1]=num_pairs
constexpr int ZERO_FLOATS = 8211; // sums + cnt + total + ctr1 + ctr2

__device__ __forceinline__ float dot4(float4 a, float4 b) {
    return a.x * b.x + a.y * b.y + a.z * b.z + a.w * b.w;
}

// ---------------------------------------------------------------- K1: class sums + counts (+ fused centroid/pair epilogue)
// 512 threads = 8 waves = 4 row-streams x 2 dim-halves. Wave-uniform label
// -> readfirstlane -> SGPR select feeding fmac. Unroll-8 rows: 8KB/wave of
// loads in flight. __launch_bounds__(512,4): VGPR cap 128 >= ~116 needed,
// so the float4 acc[16] accumulator stays in REAL VGPRs (round-2's
// VGPR_Count=56 + 82MB WRITE_SIZE showed it was being spilled).
// 16 waves/CU resident (VGPR-limited), grid 512 = 2 blocks/CU exact.
__global__ __launch_bounds__(512, 4) void k1_sums(const float* __restrict__ emb,
                                                  const int* __restrict__ labels,
                                                  float* __restrict__ ws,
                                                  int N, int rpb) {
    __shared__ float lacc[kC * kD];   // 32 KB
    __shared__ int lastblk;
    float* sums  = ws + SUMS_OFF;
    float* cnt_g = ws + CNT_OFF;
    float* cn_g  = ws + CN_OFF;
    float* pdm_g = ws + PDM_OFF;
    float* scal  = ws + SCL_OFF;
    unsigned* mask_g = (unsigned*)(ws + MSK_OFF);
    int* ctr1 = (int*)(ws + CTR1_OFF);

    int tid = threadIdx.x;
    int wave = tid >> 6, lane = tid & 63;
    int half = wave & 1, strm = wave >> 1;   // strm in [0,4)

    for (int i = tid; i < kC * kD; i += 512) lacc[i] = 0.f;

    float4 acc[kC];
#pragma unroll
    for (int c = 0; c < kC; ++c) acc[c] = make_float4(0.f, 0.f, 0.f, 0.f);
    float cacc = 0.f;

    const float4* e4 = (const float4*)emb;
    int r0 = blockIdx.x * rpb;
    int r1 = min(r0 + rpb, N);
    const int o = half * 64 + lane;

    // 4 streams x unroll-8 (row step 4) -> 32 rows per group
    for (int base = r0 + strm; base < r1; base += 32) {
        float4 xb[8];
        int lab[8];
#pragma unroll
        for (int k = 0; k < 8; ++k) {
            int rk = base + 4 * k;
            bool vk = rk < r1;
            int ck = vk ? rk : base;
            xb[k] = e4[(size_t)ck * 128 + o];
            int lv = labels[ck];
            lab[k] = __builtin_amdgcn_readfirstlane(vk ? lv : -1);
        }
#pragma unroll
        for (int c = 0; c < kC; ++c) {
            float4 a = acc[c];
#pragma unroll
            for (int k = 0; k < 8; ++k) {
                float m = (lab[k] == c) ? 1.f : 0.f;   // scalar select
                a.x += m * xb[k].x;
                a.y += m * xb[k].y;
                a.z += m * xb[k].z;
                a.w += m * xb[k].w;
            }
            acc[c] = a;
        }
        if (half == 0) {
#pragma unroll
            for (int k = 0; k < 8; ++k) cacc += (lab[k] == lane) ? 1.f : 0.f;
        }
    }

    // ---- flush: staggered non-atomic LDS merge (planar: c*512 + half*256 + comp*64 + lane)
    __syncthreads();
#pragma unroll 1
    for (int s = 0; s < kC; ++s) {
        int c = (s + strm * 4) & 15;      // per step: 4 streams -> 4 disjoint classes; halves disjoint dims
        float* p = &lacc[c * kD + half * 256 + lane];
        float4 a = acc[c];
        p[0]   += a.x;
        p[64]  += a.y;
        p[128] += a.z;
        p[192] += a.w;
        __syncthreads();
    }

    // global flush, coalesced in sums-linear order (unswizzle planar)
    for (int g = tid; g < kC * kD; g += 512) {
        int c = g >> 9, d = g & 511;
        int hh = d >> 8, u = d & 255;
        int l = u >> 2, k = u & 3;
        atomicAdd(&sums[g], lacc[c * kD + hh * 256 + k * 64 + l]);
    }
    if (half == 0 && lane < kC) atomicAdd(&cnt_g[lane], cacc);

    // ---- completion counter; last block runs centroid/pair logic
    __threadfence();
    __syncthreads();
    if (tid == 0) {
        int old = atomicAdd(ctr1, 1);
        lastblk = (old == (int)gridDim.x - 1) ? 1 : 0;
    }
    __syncthreads();
    if (!lastblk) return;
    __threadfence();   // acquire before reading other blocks' sums

    // ===== k2 phase (first 256 threads do the work; barriers are uniform) =====
    int c2 = tid >> 4, sub = tid & 15;
    if (tid < 256) {
        float cntc = atomicAdd(&cnt_g[c2], 0.f);      // coherent read
        float invc = 1.f / fmaxf(cntc, 1.f);
        float sq = 0.f;
        for (int d = sub; d < kD; d += 16) {
            float v = atomicAdd(&sums[c2 * kD + d], 0.f) * invc;
            lacc[c2 * kD + d] = v;
            sq += v * v;
        }
#pragma unroll
        for (int m = 1; m < 16; m <<= 1) sq += __shfl_xor(sq, m, 64);  // 16-lane class groups
        float inv = 1.f / fmaxf(sqrtf(sq), kEps);
        for (int d = sub; d < kD; d += 16) {
            float v = lacc[c2 * kD + d] * inv;
            lacc[c2 * kD + d] = v;
            cn_g[c2 * kD + d] = v;
        }
    }
    __syncthreads();
    if (tid < 256) {
        int pi = tid >> 4, pj = tid & 15;
        float dot = 0.f;
        for (int dd = 0; dd < kD; ++dd) {
            int d = (dd + tid) & (kD - 1);
            dot += lacc[pi * kD + d] * lacc[pj * kD + d];
        }
        pdm_g[tid] = 1.f - dot;
    }
    __syncthreads();

    if (tid == 0) {
        float lc[kC];
        for (int a = 0; a < kC; ++a) lc[a] = atomicAdd(&cnt_g[a], 0.f);
        unsigned m[kC];
        for (int a = 0; a < kC; ++a) m[a] = 0u;
        float npairs = 0.f;
        for (int a = 0; a < kC; ++a)
            for (int b = a + 1; b < kC; ++b) {
                bool close = (pdm_g[a * kC + b] <= kBeta) && (lc[a] > 0.f) && (lc[b] > 0.f);
                if (close) { m[a] |= 1u << b; m[b] |= 1u << a; npairs += 1.f; }
            }
        float count = 0.f;
        for (int a = 0; a < kC; ++a) {
            mask_g[a] = m[a];
            count += (float)__popc(m[a]) * lc[a];
        }
        scal[0] = fmaxf(count, 1.f);
        scal[1] = npairs;
    }
}

// ---------------------------------------------------------------- K3: main distance pass (+ fused final epilogue)
// Centroids in registers (wreg[4][8]); embeddings direct from global.
// Depth-3 rotating pipeline: while computing a row, TWO rows of loads are
// in flight (16KB/wave vs 8KB at depth-2). VGPR ~245 under the
// launch_bounds(512,2) cap of 256.
__global__ __launch_bounds__(512, 2) void k3_main(const float* __restrict__ emb,
                                                  const int* __restrict__ labels,
                                                  float* __restrict__ ws,
                                                  float* __restrict__ out,
                                                  int N, int rpb) {
    __shared__ unsigned lmask[kC];
    __shared__ float wsum[8];
    const float* cn_g = ws + CN_OFF;
    const unsigned* mask_g = (const unsigned*)(ws + MSK_OFF);
    float* total = ws + TOT_OFF;
    const float* scal = ws + SCL_OFF;
    int* ctr2 = (int*)(ws + CTR2_OFF);

    int tid = threadIdx.x;
    int wave = tid >> 6, lane = tid & 63;
    int g = lane >> 4, j = lane & 15;

    const float4* w4 = (const float4*)cn_g;
    float4 wreg[4][8];
#pragma unroll
    for (int c = 0; c < 4; ++c)
#pragma unroll
        for (int i = 0; i < 8; ++i)
            wreg[c][i] = w4[(4 * g + c) * 128 + i * 16 + j];
    if (tid < kC) lmask[tid] = mask_g[tid];
    __syncthreads();

    int r0 = blockIdx.x * rpb;
    int r1 = min(r0 + rpb, N);
    const float4* src = (const float4*)emb;
    float priv = 0.f;

#define LOADX(B, L, ROW)                                                       \
    do {                                                                       \
        int _r = (ROW);                                                        \
        _Pragma("unroll")                                                      \
        for (int i = 0; i < 8; ++i) B[i] = src[(size_t)_r * 128 + i * 16 + j]; \
        L = labels[_r];                                                        \
    } while (0)

#define K3_COMPUTE(X, LAB)                                                     \
    do {                                                                       \
        float d0 = 0.f, d1 = 0.f, d2 = 0.f, d3 = 0.f, nrm = 0.f;               \
        _Pragma("unroll")                                                      \
        for (int i = 0; i < 8; ++i) {                                          \
            float4 x = X[i];                                                   \
            nrm += dot4(x, x);                                                 \
            d0 += dot4(x, wreg[0][i]);                                         \
            d1 += dot4(x, wreg[1][i]);                                         \
            d2 += dot4(x, wreg[2][i]);                                         \
            d3 += dot4(x, wreg[3][i]);                                         \
        }                                                                      \
        _Pragma("unroll")                                                      \
        for (int m = 1; m < 16; m <<= 1) {                                     \
            d0 += __shfl_xor(d0, m, 64);                                       \
            d1 += __shfl_xor(d1, m, 64);                                       \
            d2 += __shfl_xor(d2, m, 64);                                       \
            d3 += __shfl_xor(d3, m, 64);                                       \
            nrm += __shfl_xor(nrm, m, 64);                                     \
        }                                                                      \
        if (j == 0) {                                                          \
            unsigned mm = lmask[LAB];                                          \
            float inv = 1.f / fmaxf(sqrtf(nrm), kEps);                         \
            float dv[4] = {d0, d1, d2, d3};                                    \
            float s = 0.f;                                                     \
            _Pragma("unroll")                                                  \
            for (int c = 0; c < 4; ++c) {                                      \
                int cg = 4 * g + c;                                            \
                float dd = 1.f - dv[c] * inv;                                  \
                if ((mm >> cg) & 1u) s += fmaxf(kBeta - dd, 0.f);              \
                if (cg == LAB) s += (float)__popc(mm) * fmaxf(dd - kAlpha, 0.f);\
            }                                                                  \
            priv += s;                                                         \
        }                                                                      \
    } while (0)

    int r = r0 + wave;
    if (r < r1) {
        float4 b0[8], b1[8], b2[8];
        int l0, l1, l2;
        LOADX(b0, l0, r);
        bool v1 = (r + 8) < r1;
        { int rr = v1 ? r + 8 : r; LOADX(b1, l1, rr); }
        bool v2 = (r + 16) < r1;
        { int rr = v2 ? r + 16 : r; LOADX(b2, l2, rr); }
        while (true) {
            bool v3 = (r + 24) < r1;
            K3_COMPUTE(b0, l0);
            if (!v1) break;
            { int rr = v3 ? r + 24 : r + 8; LOADX(b0, l0, rr); }
            bool v4 = (r + 32) < r1;
            K3_COMPUTE(b1, l1);
            if (!v2) break;
            { int rr = v4 ? r + 32 : r + 8; LOADX(b1, l1, rr); }
            bool v5 = (r + 40) < r1;
            K3_COMPUTE(b2, l2);
            if (!v3) break;
            { int rr = v5 ? r + 40 : r + 8; LOADX(b2, l2, rr); }
            r += 24;
            v1 = v4;
            v2 = v5;
        }
    }
#undef K3_COMPUTE
#undef LOADX

    // block reduce
#pragma unroll
    for (int off = 32; off > 0; off >>= 1) priv += __shfl_down(priv, off, 64);
    if (lane == 0) wsum[wave] = priv;
    __syncthreads();
    if (tid == 0) {
        float t = 0.f;
#pragma unroll
        for (int w = 0; w < 8; ++w) t += wsum[w];
        atomicAdd(total, t);
        __threadfence();
        int old = atomicAdd(ctr2, 1);
        if (old == (int)gridDim.x - 1) {
            float tot = atomicAdd(total, 0.f);   // coherent read
            out[0] = (scal[1] > 0.f) ? (tot / scal[0]) : 0.f;
        }
    }
}

extern "C" void kernel_launch(void* const* d_in, const int* in_sizes, int n_in,
                              void* d_out, int out_size, void* d_ws, size_t ws_size,
                              hipStream_t stream) {
    const float* emb = (const float*)d_in[0];
    const int* labels = (const int*)d_in[1];
    int N = in_sizes[0] / kD;

    float* ws = (float*)d_ws;
    hipMemsetAsync(d_ws, 0, ZERO_FLOATS * sizeof(float), stream);

    int blocks1 = 512;                        // 2 blocks/CU exact (16 waves/CU @ VGPR<=128)
    int rpb1 = (N + blocks1 - 1) / blocks1;
    k1_sums<<<blocks1, 512, 0, stream>>>(emb, labels, ws, N, rpb1);

    int blocks3 = 256;                        // 1 block/CU (8 waves @ ~245 VGPR)
    int rpb3 = (N + blocks3 - 1) / blocks3;
    k3_main<<<blocks3, 512, 0, stream>>>(emb, labels, ws, (float*)d_out, N, rpb3);
}

// Round 4
// 680.610 us; speedup vs baseline: 1.2361x; 1.2361x over previous
//
#include <hip/hip_runtime.h>

constexpr float kAlpha = 0.1f;
constexpr float kBeta  = 1.1f;
constexpr int   kC     = 16;
constexpr int   kD     = 512;
constexpr float kEps   = 1e-8f;

// ws layout (float offsets)
constexpr int SUMS_OFF = 0;       // kC*kD = 8192
constexpr int CNT_OFF  = 8192;    // 16
constexpr int TOT_OFF  = 8208;    // 1
constexpr int CTR1_OFF = 8209;    // int: k1 completion counter
constexpr int CTR2_OFF = 8210;    // int: k3 completion counter
constexpr int PDM_OFF  = 8960;    // 256 floats scratch (pair distances)
constexpr int CN_OFF   = 9216;    // 8192 (16B aligned)
constexpr int MSK_OFF  = 17408;   // 16 unsigned
constexpr int SCL_OFF  = 17424;   // [0]=denom, [1]=num_pairs
constexpr int ZERO_FLOATS = 8211; // sums + cnt + total + ctr1 + ctr2

__device__ __forceinline__ float dot4(float4 a, float4 b) {
    return a.x * b.x + a.y * b.y + a.z * b.z + a.w * b.w;
}

// DPP row-suffix-sum: after 4 steps, lane (l&15)==15 of each 16-lane DPP row
// holds the sum of its row. Pure VALU (v_mov_dpp + v_add), no DS pipe.
template <int CTRL>
__device__ __forceinline__ float dpp_add(float v) {
    int t = __builtin_amdgcn_update_dpp(0, __float_as_int(v), CTRL, 0xF, 0xF, true);
    return v + __int_as_float(t);
}
__device__ __forceinline__ float row16_sum(float v) {
    v = dpp_add<0x111>(v);   // row_shr:1
    v = dpp_add<0x112>(v);   // row_shr:2
    v = dpp_add<0x114>(v);   // row_shr:4
    v = dpp_add<0x118>(v);   // row_shr:8
    return v;                // valid in lane 15 of each row16
}

// ---------------------------------------------------------------- K1: class sums + counts (+ fused centroid/pair epilogue)
// (unchanged from round 3 -- fits the 128-VGPR cap: acc 64 + xb 32 + misc)
__global__ __launch_bounds__(512, 4) void k1_sums(const float* __restrict__ emb,
                                                  const int* __restrict__ labels,
                                                  float* __restrict__ ws,
                                                  int N, int rpb) {
    __shared__ float lacc[kC * kD];   // 32 KB
    __shared__ int lastblk;
    float* sums  = ws + SUMS_OFF;
    float* cnt_g = ws + CNT_OFF;
    float* cn_g  = ws + CN_OFF;
    float* pdm_g = ws + PDM_OFF;
    float* scal  = ws + SCL_OFF;
    unsigned* mask_g = (unsigned*)(ws + MSK_OFF);
    int* ctr1 = (int*)(ws + CTR1_OFF);

    int tid = threadIdx.x;
    int wave = tid >> 6, lane = tid & 63;
    int half = wave & 1, strm = wave >> 1;   // strm in [0,4)

    for (int i = tid; i < kC * kD; i += 512) lacc[i] = 0.f;

    float4 acc[kC];
#pragma unroll
    for (int c = 0; c < kC; ++c) acc[c] = make_float4(0.f, 0.f, 0.f, 0.f);
    float cacc = 0.f;

    const float4* e4 = (const float4*)emb;
    int r0 = blockIdx.x * rpb;
    int r1 = min(r0 + rpb, N);
    const int o = half * 64 + lane;

    for (int base = r0 + strm; base < r1; base += 32) {
        float4 xb[8];
        int lab[8];
#pragma unroll
        for (int k = 0; k < 8; ++k) {
            int rk = base + 4 * k;
            bool vk = rk < r1;
            int ck = vk ? rk : base;
            xb[k] = e4[(size_t)ck * 128 + o];
            int lv = labels[ck];
            lab[k] = __builtin_amdgcn_readfirstlane(vk ? lv : -1);
        }
#pragma unroll
        for (int c = 0; c < kC; ++c) {
            float4 a = acc[c];
#pragma unroll
            for (int k = 0; k < 8; ++k) {
                float m = (lab[k] == c) ? 1.f : 0.f;   // scalar select
                a.x += m * xb[k].x;
                a.y += m * xb[k].y;
                a.z += m * xb[k].z;
                a.w += m * xb[k].w;
            }
            acc[c] = a;
        }
        if (half == 0) {
#pragma unroll
            for (int k = 0; k < 8; ++k) cacc += (lab[k] == lane) ? 1.f : 0.f;
        }
    }

    // ---- flush: staggered non-atomic LDS merge (planar: c*512 + half*256 + comp*64 + lane)
    __syncthreads();
#pragma unroll 1
    for (int s = 0; s < kC; ++s) {
        int c = (s + strm * 4) & 15;
        float* p = &lacc[c * kD + half * 256 + lane];
        float4 a = acc[c];
        p[0]   += a.x;
        p[64]  += a.y;
        p[128] += a.z;
        p[192] += a.w;
        __syncthreads();
    }

    // global flush, coalesced in sums-linear order (unswizzle planar)
    for (int g = tid; g < kC * kD; g += 512) {
        int c = g >> 9, d = g & 511;
        int hh = d >> 8, u = d & 255;
        int l = u >> 2, k = u & 3;
        atomicAdd(&sums[g], lacc[c * kD + hh * 256 + k * 64 + l]);
    }
    if (half == 0 && lane < kC) atomicAdd(&cnt_g[lane], cacc);

    // ---- completion counter; last block runs centroid/pair logic
    __threadfence();
    __syncthreads();
    if (tid == 0) {
        int old = atomicAdd(ctr1, 1);
        lastblk = (old == (int)gridDim.x - 1) ? 1 : 0;
    }
    __syncthreads();
    if (!lastblk) return;
    __threadfence();

    // ===== k2 phase =====
    int c2 = tid >> 4, sub = tid & 15;
    if (tid < 256) {
        float cntc = atomicAdd(&cnt_g[c2], 0.f);
        float invc = 1.f / fmaxf(cntc, 1.f);
        float sq = 0.f;
        for (int d = sub; d < kD; d += 16) {
            float v = atomicAdd(&sums[c2 * kD + d], 0.f) * invc;
            lacc[c2 * kD + d] = v;
            sq += v * v;
        }
#pragma unroll
        for (int m = 1; m < 16; m <<= 1) sq += __shfl_xor(sq, m, 64);
        float inv = 1.f / fmaxf(sqrtf(sq), kEps);
        for (int d = sub; d < kD; d += 16) {
            float v = lacc[c2 * kD + d] * inv;
            lacc[c2 * kD + d] = v;
            cn_g[c2 * kD + d] = v;
        }
    }
    __syncthreads();
    if (tid < 256) {
        int pi = tid >> 4, pj = tid & 15;
        float dot = 0.f;
        for (int dd = 0; dd < kD; ++dd) {
            int d = (dd + tid) & (kD - 1);
            dot += lacc[pi * kD + d] * lacc[pj * kD + d];
        }
        pdm_g[tid] = 1.f - dot;
    }
    __syncthreads();

    if (tid == 0) {
        float lc[kC];
        for (int a = 0; a < kC; ++a) lc[a] = atomicAdd(&cnt_g[a], 0.f);
        unsigned m[kC];
        for (int a = 0; a < kC; ++a) m[a] = 0u;
        float npairs = 0.f;
        for (int a = 0; a < kC; ++a)
            for (int b = a + 1; b < kC; ++b) {
                bool close = (pdm_g[a * kC + b] <= kBeta) && (lc[a] > 0.f) && (lc[b] > 0.f);
                if (close) { m[a] |= 1u << b; m[b] |= 1u << a; npairs += 1.f; }
            }
        float count = 0.f;
        for (int a = 0; a < kC; ++a) {
            mask_g[a] = m[a];
            count += (float)__popc(m[a]) * lc[a];
        }
        scal[0] = fmaxf(count, 1.f);
        scal[1] = npairs;
    }
}

// ---------------------------------------------------------------- K3: main distance pass (+ fused final epilogue)
// SPILL-FREE redesign for the empirical 128-VGPR cap:
//   - wave PAIR splits the 16 classes 8/8 -> wreg[2][8] float4 = 64 VGPRs.
//     Both waves of a pair process the same rows; the second read of each
//     row hits L1/L2 on the same CU (HBM fetch unchanged).
//   - lane (g in [0,4), j in [0,16)): classes c0 = half*8 + g*2 + {0,1}.
//   - cross-lane reduce over j via DPP row_shr (VALU), NOT shfl/ds_bpermute:
//     3 values x 4 steps, result in lane j==15.
// Live state: wreg 64 + x[8] 32 + ~15 misc ~= 112 VGPR -> no spill.
// 256-thread blocks, 4 blocks/CU (16 waves/CU) for latency hiding.
__global__ __launch_bounds__(256, 4) void k3_main(const float* __restrict__ emb,
                                                  const int* __restrict__ labels,
                                                  float* __restrict__ ws,
                                                  float* __restrict__ out,
                                                  int N, int rpb) {
    __shared__ unsigned lmask[kC];
    __shared__ float wsum[4];
    const float* cn_g = ws + CN_OFF;
    const unsigned* mask_g = (const unsigned*)(ws + MSK_OFF);
    float* total = ws + TOT_OFF;
    const float* scal = ws + SCL_OFF;
    int* ctr2 = (int*)(ws + CTR2_OFF);

    int tid = threadIdx.x;
    int wave = tid >> 6, lane = tid & 63;
    int pairId = wave >> 1, halfCls = wave & 1;
    int g = lane >> 4, j = lane & 15;
    int c0 = halfCls * 8 + g * 2;           // this lane's two classes: c0, c0+1

    const float4* w4 = (const float4*)cn_g;
    float4 wreg[2][8];
#pragma unroll
    for (int t = 0; t < 2; ++t)
#pragma unroll
        for (int i = 0; i < 8; ++i)
            wreg[t][i] = w4[(c0 + t) * 128 + i * 16 + j];
    if (tid < kC) lmask[tid] = mask_g[tid];
    __syncthreads();

    int r0 = blockIdx.x * rpb;
    int r1 = min(r0 + rpb, N);
    const float4* src = (const float4*)emb;
    float priv = 0.f;

    for (int row = r0 + pairId; row < r1; row += 2) {
        float4 x[8];
#pragma unroll
        for (int i = 0; i < 8; ++i) x[i] = src[(size_t)row * 128 + i * 16 + j];
        int lab = labels[row];

        float d0 = 0.f, d1 = 0.f, nrm = 0.f;
#pragma unroll
        for (int i = 0; i < 8; ++i) {
            nrm += dot4(x[i], x[i]);
            d0  += dot4(x[i], wreg[0][i]);
            d1  += dot4(x[i], wreg[1][i]);
        }
        d0  = row16_sum(d0);
        d1  = row16_sum(d1);
        nrm = row16_sum(nrm);

        if (j == 15) {
            unsigned mm = lmask[lab];
            float inv = 1.f / fmaxf(sqrtf(nrm), kEps);
            float dd0 = 1.f - d0 * inv;
            float dd1 = 1.f - d1 * inv;
            float s = 0.f;
            if ((mm >> c0) & 1u)       s += fmaxf(kBeta - dd0, 0.f);
            if ((mm >> (c0 + 1)) & 1u) s += fmaxf(kBeta - dd1, 0.f);
            float pc = (float)__popc(mm);
            if (c0 == lab)     s += pc * fmaxf(dd0 - kAlpha, 0.f);
            if (c0 + 1 == lab) s += pc * fmaxf(dd1 - kAlpha, 0.f);
            priv += s;
        }
    }

    // block reduce (4 waves)
#pragma unroll
    for (int off = 32; off > 0; off >>= 1) priv += __shfl_down(priv, off, 64);
    if (lane == 0) wsum[wave] = priv;
    __syncthreads();
    if (tid == 0) {
        float t = wsum[0] + wsum[1] + wsum[2] + wsum[3];
        atomicAdd(total, t);
        __threadfence();
        int old = atomicAdd(ctr2, 1);
        if (old == (int)gridDim.x - 1) {
            float tot = atomicAdd(total, 0.f);
            out[0] = (scal[1] > 0.f) ? (tot / scal[0]) : 0.f;
        }
    }
}

extern "C" void kernel_launch(void* const* d_in, const int* in_sizes, int n_in,
                              void* d_out, int out_size, void* d_ws, size_t ws_size,
                              hipStream_t stream) {
    const float* emb = (const float*)d_in[0];
    const int* labels = (const int*)d_in[1];
    int N = in_sizes[0] / kD;

    float* ws = (float*)d_ws;
    hipMemsetAsync(d_ws, 0, ZERO_FLOATS * sizeof(float), stream);

    int blocks1 = 512;                        // 2 blocks/CU (16 waves/CU @ VGPR<=128)
    int rpb1 = (N + blocks1 - 1) / blocks1;
    k1_sums<<<blocks1, 512, 0, stream>>>(emb, labels, ws, N, rpb1);

    int blocks3 = 1024;                       // 4 blocks/CU x 256 thr = 16 waves/CU
    int rpb3 = (N + blocks3 - 1) / blocks3;
    k3_main<<<blocks3, 256, 0, stream>>>(emb, labels, ws, (float*)d_out, N, rpb3);
}